// Round 2
// baseline (293.545 us; speedup 1.0000x reference)
//
#include <hip/hip_runtime.h>
#include <hip/hip_bf16.h>
#include <stdint.h>

typedef unsigned short u16;
typedef __bf16 bf16x8 __attribute__((ext_vector_type(8)));
typedef float f32x4 __attribute__((ext_vector_type(4)));

#define MFMA16(a, b, c) __builtin_amdgcn_mfma_f32_16x16x32_bf16((a), (b), (c), 0, 0, 0)

#define BATCH 2
#define NSEQ 2048
#define DIMC 1024
#define NHEAD 16
#define DHEAD 64

__device__ __forceinline__ u16 f2bf(float f) {
  unsigned u = __float_as_uint(f);
  u += 0x7FFFu + ((u >> 16) & 1u);
  return (u16)(u >> 16);
}
__device__ __forceinline__ float bf2f(u16 h) {
  return __uint_as_float(((unsigned)h) << 16);
}
__device__ __forceinline__ void gload_lds16(const void* g, void* lds) {
  __builtin_amdgcn_global_load_lds((const __attribute__((address_space(1))) void*)g,
                                   (__attribute__((address_space(3))) void*)lds,
                                   16, 0, 0);
}

// ---------------------------------------------------------------------------
// fp32 -> bf16 conversion (weights)
// ---------------------------------------------------------------------------
__global__ __launch_bounds__(256) void cvt_f32_bf16(const float* __restrict__ in,
                                                    u16* __restrict__ out, int n) {
  int i = (blockIdx.x * 256 + threadIdx.x) * 4;
  if (i < n) {
    float4 v = *(const float4*)(in + i);
    ushort4 o;
    o.x = f2bf(v.x); o.y = f2bf(v.y); o.z = f2bf(v.z); o.w = f2bf(v.w);
    *(ushort4*)(out + i) = o;
  }
}

// ---------------------------------------------------------------------------
// LayerNorm: fp32 in -> bf16 out   (one block per row, 1024 cols)
// ---------------------------------------------------------------------------
__global__ __launch_bounds__(256) void ln_f32_to_bf16(const float* __restrict__ X,
                                                      const float* __restrict__ G,
                                                      const float* __restrict__ Bv,
                                                      u16* __restrict__ Y) {
  const int row = blockIdx.x;
  const int tid = threadIdx.x;
  const float4 v = *(const float4*)(X + (size_t)row * DIMC + tid * 4);
  float s = v.x + v.y + v.z + v.w;
  float q = v.x * v.x + v.y * v.y + v.z * v.z + v.w * v.w;
#pragma unroll
  for (int d = 1; d < 64; d <<= 1) {
    s += __shfl_xor(s, d, 64);
    q += __shfl_xor(q, d, 64);
  }
  __shared__ float ps[4], pq[4];
  const int w = tid >> 6, l = tid & 63;
  if (l == 0) { ps[w] = s; pq[w] = q; }
  __syncthreads();
  s = ps[0] + ps[1] + ps[2] + ps[3];
  q = pq[0] + pq[1] + pq[2] + pq[3];
  const float mean = s * (1.f / DIMC);
  const float var = q * (1.f / DIMC) - mean * mean;
  const float rs = rsqrtf(var + 1e-5f);
  const float4 g = *(const float4*)(G + tid * 4);
  const float4 bb = *(const float4*)(Bv + tid * 4);
  ushort4 o;
  o.x = f2bf((v.x - mean) * rs * g.x + bb.x);
  o.y = f2bf((v.y - mean) * rs * g.y + bb.y);
  o.z = f2bf((v.z - mean) * rs * g.z + bb.z);
  o.w = f2bf((v.w - mean) * rs * g.w + bb.w);
  *(ushort4*)(Y + (size_t)row * DIMC + tid * 4) = o;
}

// LayerNorm: bf16 in -> fp32 out
__global__ __launch_bounds__(256) void ln_bf16_to_f32(const u16* __restrict__ X,
                                                      const float* __restrict__ G,
                                                      const float* __restrict__ Bv,
                                                      float* __restrict__ Y) {
  const int row = blockIdx.x;
  const int tid = threadIdx.x;
  const ushort4 hv = *(const ushort4*)(X + (size_t)row * DIMC + tid * 4);
  float x0 = bf2f(hv.x), x1 = bf2f(hv.y), x2 = bf2f(hv.z), x3 = bf2f(hv.w);
  float s = x0 + x1 + x2 + x3;
  float q = x0 * x0 + x1 * x1 + x2 * x2 + x3 * x3;
#pragma unroll
  for (int d = 1; d < 64; d <<= 1) {
    s += __shfl_xor(s, d, 64);
    q += __shfl_xor(q, d, 64);
  }
  __shared__ float ps[4], pq[4];
  const int w = tid >> 6, l = tid & 63;
  if (l == 0) { ps[w] = s; pq[w] = q; }
  __syncthreads();
  s = ps[0] + ps[1] + ps[2] + ps[3];
  q = pq[0] + pq[1] + pq[2] + pq[3];
  const float mean = s * (1.f / DIMC);
  const float var = q * (1.f / DIMC) - mean * mean;
  const float rs = rsqrtf(var + 1e-5f);
  const float4 g = *(const float4*)(G + tid * 4);
  const float4 bb = *(const float4*)(Bv + tid * 4);
  float4 o;
  o.x = (x0 - mean) * rs * g.x + bb.x;
  o.y = (x1 - mean) * rs * g.y + bb.y;
  o.z = (x2 - mean) * rs * g.z + bb.z;
  o.w = (x3 - mean) * rs * g.w + bb.w;
  *(float4*)(Y + (size_t)row * DIMC + tid * 4) = o;
}

// ---------------------------------------------------------------------------
// GEMM  C[M,N] = A[M,K] @ Bw[N,K]^T   (bf16 in, fp32 acc)
// 128x128 tile, BK=32, 256 threads (4 waves, 2x2), each wave 64x64 (4x4 frags)
// MODE 0: out0[m][n] = bf16(acc * scale0)
// MODE 1 (KV proj, N=128): cols 0-63 -> k[m][64]*sqs ; cols 64-127 -> vT[b][d][n]
// ---------------------------------------------------------------------------
template <int MODE>
__global__ __launch_bounds__(256) void gemm_bt(const u16* __restrict__ A,
                                               const u16* __restrict__ Bw,
                                               u16* __restrict__ out0,
                                               u16* __restrict__ out1,
                                               int M, int N, int K, float scale0) {
  const int tid = threadIdx.x;
  const int w = tid >> 6, l = tid & 63;
  const int wr = w >> 1, wc = w & 1;
  const int lr = l & 15, lg = l >> 4;
  const int m0 = blockIdx.y * 128, n0 = blockIdx.x * 128;

  __shared__ u16 As[128 * 32];
  __shared__ u16 Bs[128 * 32];

  f32x4 acc[4][4] = {};

  const int nk = K >> 5;
  for (int kt = 0; kt < nk; ++kt) {
    __syncthreads();
#pragma unroll
    for (int r = 0; r < 2; ++r) {
      const int c = w * 2 + r;            // chunk 0..7, 1 KiB each
      const int lo = c * 1024 + l * 16;   // byte offset in tile
      const int row = lo >> 6;            // 64 B per row (32 bf16)
      const int cb = lo & 63;
      const char* ga = (const char*)A + ((size_t)(m0 + row) * K + (kt << 5)) * 2 + cb;
      gload_lds16(ga, (char*)As + c * 1024);
      const char* gb = (const char*)Bw + ((size_t)(n0 + row) * K + (kt << 5)) * 2 + cb;
      gload_lds16(gb, (char*)Bs + c * 1024);
    }
    __syncthreads();

    bf16x8 af[4], bfr[4];
#pragma unroll
    for (int mi = 0; mi < 4; ++mi)
      af[mi] = *(const bf16x8*)((const char*)As + ((wr * 64 + mi * 16 + lr) * 32 + lg * 8) * 2);
#pragma unroll
    for (int ni = 0; ni < 4; ++ni)
      bfr[ni] = *(const bf16x8*)((const char*)Bs + ((wc * 64 + ni * 16 + lr) * 32 + lg * 8) * 2);
#pragma unroll
    for (int mi = 0; mi < 4; ++mi)
#pragma unroll
      for (int ni = 0; ni < 4; ++ni)
        acc[mi][ni] = MFMA16(af[mi], bfr[ni], acc[mi][ni]);
  }

  if constexpr (MODE == 0) {
#pragma unroll
    for (int mi = 0; mi < 4; ++mi)
#pragma unroll
      for (int ni = 0; ni < 4; ++ni)
#pragma unroll
        for (int r = 0; r < 4; ++r) {
          const int row = m0 + wr * 64 + mi * 16 + lg * 4 + r;
          const int col = n0 + wc * 64 + ni * 16 + lr;
          out0[(size_t)row * N + col] = f2bf(acc[mi][ni][r] * scale0);
        }
  } else {
    const float sqs = 0.35355339059327379f;
#pragma unroll
    for (int mi = 0; mi < 4; ++mi)
#pragma unroll
      for (int ni = 0; ni < 4; ++ni)
#pragma unroll
        for (int r = 0; r < 4; ++r) {
          const int m = m0 + wr * 64 + mi * 16 + lg * 4 + r;  // b*2048+n
          const int b = m >> 11, n = m & 2047;
          const int colw = wc * 64 + ni * 16 + lr;
          const float vv = acc[mi][ni][r];
          if (colw < 64) {
            out0[(size_t)m * 64 + colw] = f2bf(vv * sqs);                       // k
          } else {
            const int d = colw - 64;
            out1[((size_t)b * 64 + d) * NSEQ + n] = f2bf(vv);                   // vT
          }
        }
  }
}

// ---------------------------------------------------------------------------
// Causal flash attention (MQA: shared K/V per batch).
// Block = 256 thr (4 waves), 64 Q-rows; each wave 16 rows. KV tiles of 64.
// K/Vt staged via global_load_lds with XOR-swizzled source, swizzled reads.
// ---------------------------------------------------------------------------
__global__ __launch_bounds__(256) void attn_causal(const u16* __restrict__ Q,
                                                   const u16* __restrict__ Kg,
                                                   const u16* __restrict__ VTg,
                                                   u16* __restrict__ O) {
  const int qt = blockIdx.x;  // 0..31
  const int bh = blockIdx.y;  // 0..31
  const int b = bh >> 4, h = bh & 15;
  const int tid = threadIdx.x;
  const int w = tid >> 6, l = tid & 63;
  const int lr = l & 15, lg = l >> 4;

  __shared__ u16 Ks[64 * 64];      // [kv][d], swizzled
  __shared__ u16 Vs[64 * 64];      // [d][kv] (V^T), swizzled
  __shared__ u16 Ps[4][16 * 64];   // per-wave P, swizzled

  const int qrow = qt * 64 + w * 16 + lr;
  const size_t qbase = ((size_t)(b * NSEQ + qrow)) * DIMC + h * DHEAD;
  const bf16x8 aq0 = *(const bf16x8*)(Q + qbase + lg * 8);
  const bf16x8 aq1 = *(const bf16x8*)(Q + qbase + 32 + lg * 8);

  const char* kb = (const char*)(Kg + (size_t)b * NSEQ * DHEAD);
  const char* vb = (const char*)(VTg + (size_t)b * DHEAD * NSEQ);

  float m_run[4], l_run[4];
  f32x4 oacc[4];
#pragma unroll
  for (int r = 0; r < 4; ++r) { m_run[r] = -1e30f; l_run[r] = 0.f; }
#pragma unroll
  for (int f = 0; f < 4; ++f) oacc[f] = f32x4{0.f, 0.f, 0.f, 0.f};

  for (int kt = 0; kt <= qt; ++kt) {
    __syncthreads();  // previous tile fully consumed
#pragma unroll
    for (int r = 0; r < 2; ++r) {
      const int c = w * 2 + r;
      const int lo = c * 1024 + l * 16;
      const int row = lo >> 7;   // 128 B per row
      const int pb = lo & 127;
      const int cl = pb ^ ((row & 7) << 4);  // inverse-swizzle the source
      gload_lds16(kb + (size_t)(kt * 64 + row) * 128 + cl, (char*)Ks + c * 1024);
      gload_lds16(vb + (size_t)row * (NSEQ * 2) + kt * 128 + cl, (char*)Vs + c * 1024);
    }
    __syncthreads();

    // S = Q @ K^T  -> [16 x 64] per wave
    f32x4 s[4];
#pragma unroll
    for (int f = 0; f < 4; ++f) {
      s[f] = f32x4{0.f, 0.f, 0.f, 0.f};
      const int krow = f * 16 + lr;
      const char* kr = (const char*)Ks + krow * 128;
      const int ksw = (krow & 7) << 4;
      const bf16x8 b0 = *(const bf16x8*)(kr + ((lg * 16) ^ ksw));
      const bf16x8 b1 = *(const bf16x8*)(kr + ((64 + lg * 16) ^ ksw));
      s[f] = MFMA16(aq0, b0, s[f]);
      s[f] = MFMA16(aq1, b1, s[f]);
    }

    if (kt == qt) {
#pragma unroll
      for (int f = 0; f < 4; ++f)
#pragma unroll
        for (int r = 0; r < 4; ++r)
          if (f * 16 + lr > w * 16 + lg * 4 + r) s[f][r] = -1e30f;
    }

    // online softmax (row = lg*4 + r; reduce across the 16 lanes of the group)
    float pr[4][4];
#pragma unroll
    for (int r = 0; r < 4; ++r) {
      float mx = fmaxf(fmaxf(s[0][r], s[1][r]), fmaxf(s[2][r], s[3][r]));
#pragma unroll
      for (int d = 1; d < 16; d <<= 1) mx = fmaxf(mx, __shfl_xor(mx, d, 64));
      const float mnew = fmaxf(m_run[r], mx);
      const float sc = __expf(m_run[r] - mnew);
      float ls = 0.f;
#pragma unroll
      for (int f = 0; f < 4; ++f) {
        const float p = __expf(s[f][r] - mnew);
        pr[f][r] = p;
        ls += p;
      }
#pragma unroll
      for (int d = 1; d < 16; d <<= 1) ls += __shfl_xor(ls, d, 64);
      l_run[r] = l_run[r] * sc + ls;
      m_run[r] = mnew;
#pragma unroll
      for (int f = 0; f < 4; ++f) oacc[f][r] *= sc;
    }

    // P -> bf16 -> per-wave LDS (swizzled), then re-read as A-fragments
    u16* pw = &Ps[w][0];
#pragma unroll
    for (int f = 0; f < 4; ++f)
#pragma unroll
      for (int r = 0; r < 4; ++r) {
        const int row = lg * 4 + r;
        const int cbyte = (f * 16 + lr) * 2;
        *(u16*)((char*)pw + row * 128 + (cbyte ^ ((row & 7) << 4))) = f2bf(pr[f][r]);
      }

    const int psw = (lr & 7) << 4;
    const bf16x8 ap0 = *(const bf16x8*)((const char*)pw + lr * 128 + ((lg * 16) ^ psw));
    const bf16x8 ap1 = *(const bf16x8*)((const char*)pw + lr * 128 + ((64 + lg * 16) ^ psw));
#pragma unroll
    for (int f = 0; f < 4; ++f) {
      const int vrow = f * 16 + lr;
      const char* vr = (const char*)Vs + vrow * 128;
      const int vsw = (vrow & 7) << 4;
      const bf16x8 b0 = *(const bf16x8*)(vr + ((lg * 16) ^ vsw));
      const bf16x8 b1 = *(const bf16x8*)(vr + ((64 + lg * 16) ^ vsw));
      oacc[f] = MFMA16(ap0, b0, oacc[f]);
      oacc[f] = MFMA16(ap1, b1, oacc[f]);
    }
  }

  float inv[4];
#pragma unroll
  for (int r = 0; r < 4; ++r) inv[r] = 1.f / l_run[r];
#pragma unroll
  for (int f = 0; f < 4; ++f)
#pragma unroll
    for (int r = 0; r < 4; ++r) {
      const int row = qt * 64 + w * 16 + lg * 4 + r;
      const int col = h * DHEAD + f * 16 + lr;
      O[((size_t)(b * NSEQ + row)) * DIMC + col] = f2bf(oacc[f][r] * inv[r]);
    }
}

// ---------------------------------------------------------------------------
extern "C" void kernel_launch(void* const* d_in, const int* in_sizes, int n_in,
                              void* d_out, int out_size, void* d_ws, size_t ws_size,
                              hipStream_t stream) {
  const float* x = (const float*)d_in[0];
  const float* w_q = (const float*)d_in[1];
  const float* w_kv = (const float*)d_in[2];
  const float* w_out = (const float*)d_in[3];
  const float* ln_g = (const float*)d_in[4];
  const float* ln_b = (const float*)d_in[5];
  const float* lno_g = (const float*)d_in[6];
  const float* lno_b = (const float*)d_in[7];
  float* out = (float*)d_out;

  char* ws = (char*)d_ws;
  size_t off = 0;
  auto alloc = [&](size_t bytes) {
    char* p = ws + off;
    off += (bytes + 255) & ~(size_t)255;
    return p;
  };
  u16* xn   = (u16*)alloc((size_t)BATCH * NSEQ * DIMC * 2);   // 8 MiB
  u16* wqb  = (u16*)alloc((size_t)DIMC * DIMC * 2);           // 2 MiB
  u16* wkvb = (u16*)alloc((size_t)128 * DIMC * 2);            // 256 KiB
  u16* wob  = (u16*)alloc((size_t)DIMC * DIMC * 2);           // 2 MiB
  u16* qb   = (u16*)alloc((size_t)BATCH * NSEQ * DIMC * 2);   // 8 MiB
  u16* kb   = (u16*)alloc((size_t)BATCH * NSEQ * DHEAD * 2);  // 512 KiB
  u16* vtb  = (u16*)alloc((size_t)BATCH * DHEAD * NSEQ * 2);  // 512 KiB
  u16* ao = xn;  // attention output aliases xn (xn dead after projections)
  u16* yb = qb;  // pre-LN2 aliases q (q dead after attention)

  const float qscale = 0.044194173824159216f;  // scale * sqrt(scale)

  cvt_f32_bf16<<<1024, 256, 0, stream>>>(w_q, wqb, DIMC * DIMC);
  cvt_f32_bf16<<<128, 256, 0, stream>>>(w_kv, wkvb, 128 * DIMC);
  cvt_f32_bf16<<<1024, 256, 0, stream>>>(w_out, wob, DIMC * DIMC);

  ln_f32_to_bf16<<<BATCH * NSEQ, 256, 0, stream>>>(x, ln_g, ln_b, xn);

  gemm_bt<0><<<dim3(8, 32), 256, 0, stream>>>(xn, wqb, qb, nullptr,
                                              BATCH * NSEQ, DIMC, DIMC, qscale);
  gemm_bt<1><<<dim3(1, 32), 256, 0, stream>>>(xn, wkvb, kb, vtb,
                                              BATCH * NSEQ, 128, DIMC, 1.f);

  attn_causal<<<dim3(32, 32), 256, 0, stream>>>(qb, kb, vtb, ao);

  gemm_bt<0><<<dim3(8, 32), 256, 0, stream>>>(ao, wob, yb, nullptr,
                                              BATCH * NSEQ, DIMC, DIMC, 1.f);

  ln_bf16_to_f32<<<BATCH * NSEQ, 256, 0, stream>>>(yb, lno_g, lno_b, out);
}

// Round 3
// 223.663 us; speedup vs baseline: 1.3124x; 1.3124x over previous
//
#include <hip/hip_runtime.h>
#include <hip/hip_bf16.h>
#include <stdint.h>

typedef unsigned short u16;
typedef __bf16 bf16x8 __attribute__((ext_vector_type(8)));
typedef float f32x4 __attribute__((ext_vector_type(4)));

#define MFMA16(a, b, c) __builtin_amdgcn_mfma_f32_16x16x32_bf16((a), (b), (c), 0, 0, 0)

#define BATCH 2
#define NSEQ 2048
#define DIMC 1024
#define NHEAD 16
#define DHEAD 64

__device__ __forceinline__ u16 f2bf(float f) {
  unsigned u = __float_as_uint(f);
  u += 0x7FFFu + ((u >> 16) & 1u);
  return (u16)(u >> 16);
}
__device__ __forceinline__ float bf2f(u16 h) {
  return __uint_as_float(((unsigned)h) << 16);
}
__device__ __forceinline__ void gload_lds16(const void* g, void* lds) {
  __builtin_amdgcn_global_load_lds((const __attribute__((address_space(1))) void*)g,
                                   (__attribute__((address_space(3))) void*)lds,
                                   16, 0, 0);
}

// ---------------------------------------------------------------------------
// fp32 -> bf16 conversion (weights)
// ---------------------------------------------------------------------------
__global__ __launch_bounds__(256) void cvt_f32_bf16(const float* __restrict__ in,
                                                    u16* __restrict__ out, int n) {
  int i = (blockIdx.x * 256 + threadIdx.x) * 4;
  if (i < n) {
    float4 v = *(const float4*)(in + i);
    ushort4 o;
    o.x = f2bf(v.x); o.y = f2bf(v.y); o.z = f2bf(v.z); o.w = f2bf(v.w);
    *(ushort4*)(out + i) = o;
  }
}

// ---------------------------------------------------------------------------
// LayerNorm: fp32 in -> bf16 out   (one block per row, 1024 cols)
// ---------------------------------------------------------------------------
__global__ __launch_bounds__(256) void ln_f32_to_bf16(const float* __restrict__ X,
                                                      const float* __restrict__ G,
                                                      const float* __restrict__ Bv,
                                                      u16* __restrict__ Y) {
  const int row = blockIdx.x;
  const int tid = threadIdx.x;
  const float4 v = *(const float4*)(X + (size_t)row * DIMC + tid * 4);
  float s = v.x + v.y + v.z + v.w;
  float q = v.x * v.x + v.y * v.y + v.z * v.z + v.w * v.w;
#pragma unroll
  for (int d = 1; d < 64; d <<= 1) {
    s += __shfl_xor(s, d, 64);
    q += __shfl_xor(q, d, 64);
  }
  __shared__ float ps[4], pq[4];
  const int w = tid >> 6, l = tid & 63;
  if (l == 0) { ps[w] = s; pq[w] = q; }
  __syncthreads();
  s = ps[0] + ps[1] + ps[2] + ps[3];
  q = pq[0] + pq[1] + pq[2] + pq[3];
  const float mean = s * (1.f / DIMC);
  const float var = q * (1.f / DIMC) - mean * mean;
  const float rs = rsqrtf(var + 1e-5f);
  const float4 g = *(const float4*)(G + tid * 4);
  const float4 bb = *(const float4*)(Bv + tid * 4);
  ushort4 o;
  o.x = f2bf((v.x - mean) * rs * g.x + bb.x);
  o.y = f2bf((v.y - mean) * rs * g.y + bb.y);
  o.z = f2bf((v.z - mean) * rs * g.z + bb.z);
  o.w = f2bf((v.w - mean) * rs * g.w + bb.w);
  *(ushort4*)(Y + (size_t)row * DIMC + tid * 4) = o;
}

// LayerNorm: bf16 in -> fp32 out
__global__ __launch_bounds__(256) void ln_bf16_to_f32(const u16* __restrict__ X,
                                                      const float* __restrict__ G,
                                                      const float* __restrict__ Bv,
                                                      float* __restrict__ Y) {
  const int row = blockIdx.x;
  const int tid = threadIdx.x;
  const ushort4 hv = *(const ushort4*)(X + (size_t)row * DIMC + tid * 4);
  float x0 = bf2f(hv.x), x1 = bf2f(hv.y), x2 = bf2f(hv.z), x3 = bf2f(hv.w);
  float s = x0 + x1 + x2 + x3;
  float q = x0 * x0 + x1 * x1 + x2 * x2 + x3 * x3;
#pragma unroll
  for (int d = 1; d < 64; d <<= 1) {
    s += __shfl_xor(s, d, 64);
    q += __shfl_xor(q, d, 64);
  }
  __shared__ float ps[4], pq[4];
  const int w = tid >> 6, l = tid & 63;
  if (l == 0) { ps[w] = s; pq[w] = q; }
  __syncthreads();
  s = ps[0] + ps[1] + ps[2] + ps[3];
  q = pq[0] + pq[1] + pq[2] + pq[3];
  const float mean = s * (1.f / DIMC);
  const float var = q * (1.f / DIMC) - mean * mean;
  const float rs = rsqrtf(var + 1e-5f);
  const float4 g = *(const float4*)(G + tid * 4);
  const float4 bb = *(const float4*)(Bv + tid * 4);
  float4 o;
  o.x = (x0 - mean) * rs * g.x + bb.x;
  o.y = (x1 - mean) * rs * g.y + bb.y;
  o.z = (x2 - mean) * rs * g.z + bb.z;
  o.w = (x3 - mean) * rs * g.w + bb.w;
  *(float4*)(Y + (size_t)row * DIMC + tid * 4) = o;
}

// ---------------------------------------------------------------------------
// GEMM  C[M,N] = A[M,K] @ Bw[N,K]^T   (bf16 in, fp32 acc)
// 128x128 tile, BK=64, double-buffered LDS + 2-phase prefetch, XOR-swizzled.
// 256 threads (4 waves, 2x2), each wave 64x64 (4x4 frags).
// MODE 0: out0[m][n] = bf16(acc * scale0)
// MODE 1 (KV proj, N=128): cols 0-63 -> k[m][64]*sqs ; cols 64-127 -> vT[b][d][n]
// ---------------------------------------------------------------------------
template <int MODE>
__global__ __launch_bounds__(256) void gemm_bt(const u16* __restrict__ A,
                                               const u16* __restrict__ Bw,
                                               u16* __restrict__ out0,
                                               u16* __restrict__ out1,
                                               int M, int N, int K, float scale0) {
  const int tid = threadIdx.x;
  const int w = tid >> 6, l = tid & 63;
  const int wr = w >> 1, wc = w & 1;
  const int lr = l & 15, lg = l >> 4;
  const int m0 = blockIdx.y * 128, n0 = blockIdx.x * 128;

  __shared__ u16 As[2][128 * 64];   // 16 KiB each, 128B rows, XOR-swizzled
  __shared__ u16 Bs[2][128 * 64];

  f32x4 acc[4][4] = {};

  auto STAGE = [&](int buf, int kt) {
#pragma unroll
    for (int r = 0; r < 4; ++r) {
      const int c = w * 4 + r;          // chunk 0..15, 1 KiB each
      const int lo = c * 1024 + l * 16;
      const int row = lo >> 7;          // 128 B per row (64 bf16)
      const int pb = lo & 127;
      const int cl = pb ^ ((row & 7) << 4);  // inverse-swizzle source
      gload_lds16((const char*)A + ((size_t)(m0 + row) * K + kt * 64) * 2 + cl,
                  (char*)As[buf] + c * 1024);
      gload_lds16((const char*)Bw + ((size_t)(n0 + row) * K + kt * 64) * 2 + cl,
                  (char*)Bs[buf] + c * 1024);
    }
  };

  STAGE(0, 0);
  __syncthreads();
  int cur = 0;
  const int nk = K >> 6;
  for (int kt = 0; kt < nk; ++kt) {
    if (kt + 1 < nk) STAGE(cur ^ 1, kt + 1);
    const char* as = (const char*)As[cur];
    const char* bs = (const char*)Bs[cur];
#pragma unroll
    for (int ks = 0; ks < 2; ++ks) {
      bf16x8 af[4], bfr[4];
#pragma unroll
      for (int mi = 0; mi < 4; ++mi) {
        const int row = wr * 64 + mi * 16 + lr;
        af[mi] = *(const bf16x8*)(as + row * 128 + ((ks * 64 + lg * 16) ^ ((row & 7) << 4)));
      }
#pragma unroll
      for (int ni = 0; ni < 4; ++ni) {
        const int row = wc * 64 + ni * 16 + lr;
        bfr[ni] = *(const bf16x8*)(bs + row * 128 + ((ks * 64 + lg * 16) ^ ((row & 7) << 4)));
      }
#pragma unroll
      for (int mi = 0; mi < 4; ++mi)
#pragma unroll
        for (int ni = 0; ni < 4; ++ni)
          acc[mi][ni] = MFMA16(af[mi], bfr[ni], acc[mi][ni]);
    }
    __syncthreads();
    cur ^= 1;
  }

  if constexpr (MODE == 0) {
#pragma unroll
    for (int mi = 0; mi < 4; ++mi)
#pragma unroll
      for (int ni = 0; ni < 4; ++ni)
#pragma unroll
        for (int r = 0; r < 4; ++r) {
          const int row = m0 + wr * 64 + mi * 16 + lg * 4 + r;
          const int col = n0 + wc * 64 + ni * 16 + lr;
          out0[(size_t)row * N + col] = f2bf(acc[mi][ni][r] * scale0);
        }
  } else {
    const float sqs = 0.35355339059327379f;
#pragma unroll
    for (int mi = 0; mi < 4; ++mi)
#pragma unroll
      for (int ni = 0; ni < 4; ++ni)
#pragma unroll
        for (int r = 0; r < 4; ++r) {
          const int m = m0 + wr * 64 + mi * 16 + lg * 4 + r;  // b*2048+n
          const int b = m >> 11, n = m & 2047;
          const int colw = wc * 64 + ni * 16 + lr;
          const float vv = acc[mi][ni][r];
          if (colw < 64) {
            out0[(size_t)m * 64 + colw] = f2bf(vv * sqs);                       // k
          } else {
            const int d = colw - 64;
            out1[((size_t)b * 64 + d) * NSEQ + n] = f2bf(vv);                   // vT
          }
        }
  }
}

// ---------------------------------------------------------------------------
// Causal flash attention (MQA: shared K/V per batch).
// Block = 256 thr (4 waves). Each block owns TWO q-tiles {i, 31-i} -> every
// block does exactly 33 tile-computes (load-balanced). K/V double-buffered
// with 2-phase prefetch; both-sides XOR swizzle on all LDS tiles.
// ---------------------------------------------------------------------------
__global__ __launch_bounds__(256) void attn_causal(const u16* __restrict__ Q,
                                                   const u16* __restrict__ Kg,
                                                   const u16* __restrict__ VTg,
                                                   u16* __restrict__ O) {
  const int pi = blockIdx.x;      // 0..15
  const int qtA = pi, qtB = 31 - pi;
  const int bh = blockIdx.y;      // 0..31
  const int b = bh >> 4, h = bh & 15;
  const int tid = threadIdx.x;
  const int w = tid >> 6, l = tid & 63;
  const int lr = l & 15, lg = l >> 4;

  __shared__ u16 Ks[2][64 * 64];   // [kv][d], swizzled, double-buffered
  __shared__ u16 Vs[2][64 * 64];   // [d][kv] (V^T), swizzled, double-buffered
  __shared__ u16 Ps[4][16 * 64];   // per-wave P, swizzled

  const int qrowA = qtA * 64 + w * 16 + lr;
  const int qrowB = qtB * 64 + w * 16 + lr;
  const size_t qbA = ((size_t)(b * NSEQ + qrowA)) * DIMC + h * DHEAD;
  const size_t qbB = ((size_t)(b * NSEQ + qrowB)) * DIMC + h * DHEAD;
  const bf16x8 aqA0 = *(const bf16x8*)(Q + qbA + lg * 8);
  const bf16x8 aqA1 = *(const bf16x8*)(Q + qbA + 32 + lg * 8);
  const bf16x8 aqB0 = *(const bf16x8*)(Q + qbB + lg * 8);
  const bf16x8 aqB1 = *(const bf16x8*)(Q + qbB + 32 + lg * 8);

  const char* kb = (const char*)(Kg + (size_t)b * NSEQ * DHEAD);
  const char* vb = (const char*)(VTg + (size_t)b * DHEAD * NSEQ);

  float mA[4], lA[4], mB[4], lB[4];
  f32x4 oA[4], oB[4];
#pragma unroll
  for (int r = 0; r < 4; ++r) { mA[r] = -1e30f; lA[r] = 0.f; mB[r] = -1e30f; lB[r] = 0.f; }
#pragma unroll
  for (int f = 0; f < 4; ++f) { oA[f] = f32x4{0.f,0.f,0.f,0.f}; oB[f] = f32x4{0.f,0.f,0.f,0.f}; }

  auto STAGE = [&](int buf, int kt) {
#pragma unroll
    for (int r = 0; r < 2; ++r) {
      const int c = w * 2 + r;
      const int lo = c * 1024 + l * 16;
      const int row = lo >> 7;   // 128 B per row
      const int pb = lo & 127;
      const int cl = pb ^ ((row & 7) << 4);  // inverse-swizzle the source
      gload_lds16(kb + (size_t)(kt * 64 + row) * 128 + cl, (char*)Ks[buf] + c * 1024);
      gload_lds16(vb + (size_t)row * (NSEQ * 2) + kt * 128 + cl, (char*)Vs[buf] + c * 1024);
    }
  };

  auto TILE = [&](const bf16x8 q0, const bf16x8 q1, float* mr, float* lsum,
                  f32x4* oa, int qt, int kt, int cur) {
    // S = Q @ K^T  -> [16 x 64] per wave
    f32x4 s[4];
    __builtin_amdgcn_s_setprio(1);
#pragma unroll
    for (int f = 0; f < 4; ++f) {
      s[f] = f32x4{0.f, 0.f, 0.f, 0.f};
      const int krow = f * 16 + lr;
      const char* krp = (const char*)Ks[cur] + krow * 128;
      const int ksw = (krow & 7) << 4;
      const bf16x8 b0 = *(const bf16x8*)(krp + ((lg * 16) ^ ksw));
      const bf16x8 b1 = *(const bf16x8*)(krp + ((64 + lg * 16) ^ ksw));
      s[f] = MFMA16(q0, b0, s[f]);
      s[f] = MFMA16(q1, b1, s[f]);
    }
    __builtin_amdgcn_s_setprio(0);

    if (kt == qt) {
#pragma unroll
      for (int f = 0; f < 4; ++f)
#pragma unroll
        for (int r = 0; r < 4; ++r)
          if (f * 16 + lr > w * 16 + lg * 4 + r) s[f][r] = -1e30f;
    }

    // online softmax (row = lg*4 + r; reduce across the 16 lanes of the group)
    float pr[4][4];
#pragma unroll
    for (int r = 0; r < 4; ++r) {
      float mx = fmaxf(fmaxf(s[0][r], s[1][r]), fmaxf(s[2][r], s[3][r]));
#pragma unroll
      for (int d = 1; d < 16; d <<= 1) mx = fmaxf(mx, __shfl_xor(mx, d, 64));
      const float mnew = fmaxf(mr[r], mx);
      const float sc = __expf(mr[r] - mnew);
      float ls = 0.f;
#pragma unroll
      for (int f = 0; f < 4; ++f) {
        const float p = __expf(s[f][r] - mnew);
        pr[f][r] = p;
        ls += p;
      }
#pragma unroll
      for (int d = 1; d < 16; d <<= 1) ls += __shfl_xor(ls, d, 64);
      lsum[r] = lsum[r] * sc + ls;
      mr[r] = mnew;
#pragma unroll
      for (int f = 0; f < 4; ++f) oa[f][r] *= sc;
    }

    // P -> bf16 -> per-wave LDS (swizzled), then re-read as A-fragments
    u16* pw = &Ps[w][0];
#pragma unroll
    for (int f = 0; f < 4; ++f)
#pragma unroll
      for (int r = 0; r < 4; ++r) {
        const int row = lg * 4 + r;
        const int cbyte = (f * 16 + lr) * 2;
        *(u16*)((char*)pw + row * 128 + (cbyte ^ ((row & 7) << 4))) = f2bf(pr[f][r]);
      }

    const int psw = (lr & 7) << 4;
    const bf16x8 ap0 = *(const bf16x8*)((const char*)pw + lr * 128 + ((lg * 16) ^ psw));
    const bf16x8 ap1 = *(const bf16x8*)((const char*)pw + lr * 128 + ((64 + lg * 16) ^ psw));
    __builtin_amdgcn_s_setprio(1);
#pragma unroll
    for (int f = 0; f < 4; ++f) {
      const int vrow = f * 16 + lr;
      const char* vr = (const char*)Vs[cur] + vrow * 128;
      const int vsw = (vrow & 7) << 4;
      const bf16x8 b0 = *(const bf16x8*)(vr + ((lg * 16) ^ vsw));
      const bf16x8 b1 = *(const bf16x8*)(vr + ((64 + lg * 16) ^ vsw));
      oa[f] = MFMA16(ap0, b0, oa[f]);
      oa[f] = MFMA16(ap1, b1, oa[f]);
    }
    __builtin_amdgcn_s_setprio(0);
  };

  STAGE(0, 0);
  __syncthreads();
  int cur = 0;
  const int nkt = qtB + 1;
  for (int kt = 0; kt < nkt; ++kt) {
    if (kt + 1 < nkt) STAGE(cur ^ 1, kt + 1);
    if (kt <= qtA) TILE(aqA0, aqA1, mA, lA, oA, qtA, kt, cur);
    TILE(aqB0, aqB1, mB, lB, oB, qtB, kt, cur);
    __syncthreads();
    cur ^= 1;
  }

  float invA[4], invB[4];
#pragma unroll
  for (int r = 0; r < 4; ++r) { invA[r] = 1.f / lA[r]; invB[r] = 1.f / lB[r]; }
#pragma unroll
  for (int f = 0; f < 4; ++f)
#pragma unroll
    for (int r = 0; r < 4; ++r) {
      const int col = h * DHEAD + f * 16 + lr;
      const int rowA = qtA * 64 + w * 16 + lg * 4 + r;
      O[((size_t)(b * NSEQ + rowA)) * DIMC + col] = f2bf(oA[f][r] * invA[r]);
      const int rowB = qtB * 64 + w * 16 + lg * 4 + r;
      O[((size_t)(b * NSEQ + rowB)) * DIMC + col] = f2bf(oB[f][r] * invB[r]);
    }
}

// ---------------------------------------------------------------------------
extern "C" void kernel_launch(void* const* d_in, const int* in_sizes, int n_in,
                              void* d_out, int out_size, void* d_ws, size_t ws_size,
                              hipStream_t stream) {
  const float* x = (const float*)d_in[0];
  const float* w_q = (const float*)d_in[1];
  const float* w_kv = (const float*)d_in[2];
  const float* w_out = (const float*)d_in[3];
  const float* ln_g = (const float*)d_in[4];
  const float* ln_b = (const float*)d_in[5];
  const float* lno_g = (const float*)d_in[6];
  const float* lno_b = (const float*)d_in[7];
  float* out = (float*)d_out;

  char* ws = (char*)d_ws;
  size_t off = 0;
  auto alloc = [&](size_t bytes) {
    char* p = ws + off;
    off += (bytes + 255) & ~(size_t)255;
    return p;
  };
  u16* xn   = (u16*)alloc((size_t)BATCH * NSEQ * DIMC * 2);   // 8 MiB
  u16* wqb  = (u16*)alloc((size_t)DIMC * DIMC * 2);           // 2 MiB
  u16* wkvb = (u16*)alloc((size_t)128 * DIMC * 2);            // 256 KiB
  u16* wob  = (u16*)alloc((size_t)DIMC * DIMC * 2);           // 2 MiB
  u16* qb   = (u16*)alloc((size_t)BATCH * NSEQ * DIMC * 2);   // 8 MiB
  u16* kb   = (u16*)alloc((size_t)BATCH * NSEQ * DHEAD * 2);  // 512 KiB
  u16* vtb  = (u16*)alloc((size_t)BATCH * DHEAD * NSEQ * 2);  // 512 KiB
  u16* ao = xn;  // attention output aliases xn (xn dead after projections)
  u16* yb = qb;  // pre-LN2 aliases q (q dead after attention)

  const float qscale = 0.044194173824159216f;  // scale * sqrt(scale)

  cvt_f32_bf16<<<1024, 256, 0, stream>>>(w_q, wqb, DIMC * DIMC);
  cvt_f32_bf16<<<128, 256, 0, stream>>>(w_kv, wkvb, 128 * DIMC);
  cvt_f32_bf16<<<1024, 256, 0, stream>>>(w_out, wob, DIMC * DIMC);

  ln_f32_to_bf16<<<BATCH * NSEQ, 256, 0, stream>>>(x, ln_g, ln_b, xn);

  gemm_bt<0><<<dim3(8, 32), 256, 0, stream>>>(xn, wqb, qb, nullptr,
                                              BATCH * NSEQ, DIMC, DIMC, qscale);
  gemm_bt<1><<<dim3(1, 32), 256, 0, stream>>>(xn, wkvb, kb, vtb,
                                              BATCH * NSEQ, 128, DIMC, 1.f);

  attn_causal<<<dim3(16, 32), 256, 0, stream>>>(qb, kb, vtb, ao);

  gemm_bt<0><<<dim3(8, 32), 256, 0, stream>>>(ao, wob, yb, nullptr,
                                              BATCH * NSEQ, DIMC, DIMC, 1.f);

  ln_bf16_to_f32<<<BATCH * NSEQ, 256, 0, stream>>>(yb, lno_g, lno_b, out);
}

// Round 4
// 210.730 us; speedup vs baseline: 1.3930x; 1.0614x over previous
//
#include <hip/hip_runtime.h>
#include <hip/hip_bf16.h>
#include <stdint.h>

typedef unsigned short u16;
typedef __bf16 bf16x8 __attribute__((ext_vector_type(8)));
typedef float f32x4 __attribute__((ext_vector_type(4)));

#define MFMA16(a, b, c) __builtin_amdgcn_mfma_f32_16x16x32_bf16((a), (b), (c), 0, 0, 0)

#define BATCH 2
#define NSEQ 2048
#define DIMC 1024
#define NHEAD 16
#define DHEAD 64

__device__ __forceinline__ u16 f2bf(float f) {
  unsigned u = __float_as_uint(f);
  u += 0x7FFFu + ((u >> 16) & 1u);
  return (u16)(u >> 16);
}
__device__ __forceinline__ float bf2f(u16 h) {
  return __uint_as_float(((unsigned)h) << 16);
}
__device__ __forceinline__ void gload_lds16(const void* g, void* lds) {
  __builtin_amdgcn_global_load_lds((const __attribute__((address_space(1))) void*)g,
                                   (__attribute__((address_space(3))) void*)lds,
                                   16, 0, 0);
}
// counted-vmcnt waits (immediates must be literals)
#define WAIT_VM(N) asm volatile("s_waitcnt vmcnt(" #N ")" ::: "memory")
#define BARRIER() __builtin_amdgcn_s_barrier()

// ---------------------------------------------------------------------------
// fp32 -> bf16 conversion (weights)
// ---------------------------------------------------------------------------
__global__ __launch_bounds__(256) void cvt_f32_bf16(const float* __restrict__ in,
                                                    u16* __restrict__ out, int n) {
  int i = (blockIdx.x * 256 + threadIdx.x) * 4;
  if (i < n) {
    float4 v = *(const float4*)(in + i);
    ushort4 o;
    o.x = f2bf(v.x); o.y = f2bf(v.y); o.z = f2bf(v.z); o.w = f2bf(v.w);
    *(ushort4*)(out + i) = o;
  }
}

// ---------------------------------------------------------------------------
// LayerNorm: fp32 in -> bf16 out   (one block per row, 1024 cols)
// ---------------------------------------------------------------------------
__global__ __launch_bounds__(256) void ln_f32_to_bf16(const float* __restrict__ X,
                                                      const float* __restrict__ G,
                                                      const float* __restrict__ Bv,
                                                      u16* __restrict__ Y) {
  const int row = blockIdx.x;
  const int tid = threadIdx.x;
  const float4 v = *(const float4*)(X + (size_t)row * DIMC + tid * 4);
  float s = v.x + v.y + v.z + v.w;
  float q = v.x * v.x + v.y * v.y + v.z * v.z + v.w * v.w;
#pragma unroll
  for (int d = 1; d < 64; d <<= 1) {
    s += __shfl_xor(s, d, 64);
    q += __shfl_xor(q, d, 64);
  }
  __shared__ float ps[4], pq[4];
  const int w = tid >> 6, l = tid & 63;
  if (l == 0) { ps[w] = s; pq[w] = q; }
  __syncthreads();
  s = ps[0] + ps[1] + ps[2] + ps[3];
  q = pq[0] + pq[1] + pq[2] + pq[3];
  const float mean = s * (1.f / DIMC);
  const float var = q * (1.f / DIMC) - mean * mean;
  const float rs = rsqrtf(var + 1e-5f);
  const float4 g = *(const float4*)(G + tid * 4);
  const float4 bb = *(const float4*)(Bv + tid * 4);
  ushort4 o;
  o.x = f2bf((v.x - mean) * rs * g.x + bb.x);
  o.y = f2bf((v.y - mean) * rs * g.y + bb.y);
  o.z = f2bf((v.z - mean) * rs * g.z + bb.z);
  o.w = f2bf((v.w - mean) * rs * g.w + bb.w);
  *(ushort4*)(Y + (size_t)row * DIMC + tid * 4) = o;
}

// LayerNorm: bf16 in -> fp32 out
__global__ __launch_bounds__(256) void ln_bf16_to_f32(const u16* __restrict__ X,
                                                      const float* __restrict__ G,
                                                      const float* __restrict__ Bv,
                                                      float* __restrict__ Y) {
  const int row = blockIdx.x;
  const int tid = threadIdx.x;
  const ushort4 hv = *(const ushort4*)(X + (size_t)row * DIMC + tid * 4);
  float x0 = bf2f(hv.x), x1 = bf2f(hv.y), x2 = bf2f(hv.z), x3 = bf2f(hv.w);
  float s = x0 + x1 + x2 + x3;
  float q = x0 * x0 + x1 * x1 + x2 * x2 + x3 * x3;
#pragma unroll
  for (int d = 1; d < 64; d <<= 1) {
    s += __shfl_xor(s, d, 64);
    q += __shfl_xor(q, d, 64);
  }
  __shared__ float ps[4], pq[4];
  const int w = tid >> 6, l = tid & 63;
  if (l == 0) { ps[w] = s; pq[w] = q; }
  __syncthreads();
  s = ps[0] + ps[1] + ps[2] + ps[3];
  q = pq[0] + pq[1] + pq[2] + pq[3];
  const float mean = s * (1.f / DIMC);
  const float var = q * (1.f / DIMC) - mean * mean;
  const float rs = rsqrtf(var + 1e-5f);
  const float4 g = *(const float4*)(G + tid * 4);
  const float4 bb = *(const float4*)(Bv + tid * 4);
  float4 o;
  o.x = (x0 - mean) * rs * g.x + bb.x;
  o.y = (x1 - mean) * rs * g.y + bb.y;
  o.z = (x2 - mean) * rs * g.z + bb.z;
  o.w = (x3 - mean) * rs * g.w + bb.w;
  *(float4*)(Y + (size_t)row * DIMC + tid * 4) = o;
}

// ---------------------------------------------------------------------------
// GEMM  C[M,N] = A[M,K] @ Bw[N,K]^T   (bf16 in, fp32 acc)
// 128x128 tile, BK=64, dbuf + counted-vmcnt pipeline (2 raw barriers/iter),
// XOR-swizzled LDS, XCD-chunked block swizzle.
// MODE 0: out0[m][n] = bf16(acc * scale0)      (N = logical out stride)
// MODE 2: fused QKV (N=1152): col<1024 -> q*scale0 ; 1024..1087 -> k*sqs ;
//         1088..1151 -> vT[b][d][n]
// ---------------------------------------------------------------------------
template <int MODE>
__global__ __launch_bounds__(256) void gemm_bt(const u16* __restrict__ A,
                                               const u16* __restrict__ Bw,
                                               u16* __restrict__ out0,
                                               u16* __restrict__ out1,
                                               u16* __restrict__ out2,
                                               int M, int N, int K, float scale0) {
  const int tid = threadIdx.x;
  const int w = tid >> 6, l = tid & 63;
  const int wr = w >> 1, wc = w & 1;
  const int lr = l & 15, lg = l >> 4;

  // XCD-chunked bijective swizzle (requires nwg % 8 == 0)
  const int nwgx = gridDim.x;
  const int nwg = nwgx * gridDim.y;
  int flat = blockIdx.x + nwgx * blockIdx.y;
  if ((nwg & 7) == 0) flat = (flat & 7) * (nwg >> 3) + (flat >> 3);
  const int m0 = (flat / nwgx) * 128, n0 = (flat % nwgx) * 128;

  __shared__ u16 As[2][128 * 64];   // 16 KiB each, 128B rows, XOR-swizzled
  __shared__ u16 Bs[2][128 * 64];

  f32x4 acc[4][4] = {};

  auto STAGE = [&](int buf, int kt) {
#pragma unroll
    for (int r = 0; r < 4; ++r) {
      const int c = w * 4 + r;          // chunk 0..15, 1 KiB each
      const int lo = c * 1024 + l * 16;
      const int row = lo >> 7;          // 128 B per row (64 bf16)
      const int pb = lo & 127;
      const int cl = pb ^ ((row & 7) << 4);  // inverse-swizzle source
      gload_lds16((const char*)A + ((size_t)(m0 + row) * K + kt * 64) * 2 + cl,
                  (char*)As[buf] + c * 1024);
      gload_lds16((const char*)Bw + ((size_t)(n0 + row) * K + kt * 64) * 2 + cl,
                  (char*)Bs[buf] + c * 1024);
    }
  };

  const int nk = K >> 6;
  STAGE(0, 0);
  if (nk > 1) STAGE(1, 1);
  int cur = 0;
  for (int kt = 0; kt < nk; ++kt) {
    if (kt + 1 < nk) { WAIT_VM(8); } else { WAIT_VM(0); }
    BARRIER();
    const char* as = (const char*)As[cur];
    const char* bs = (const char*)Bs[cur];
#pragma unroll
    for (int ks = 0; ks < 2; ++ks) {
      bf16x8 af[4], bfr[4];
#pragma unroll
      for (int mi = 0; mi < 4; ++mi) {
        const int row = wr * 64 + mi * 16 + lr;
        af[mi] = *(const bf16x8*)(as + row * 128 + ((ks * 64 + lg * 16) ^ ((row & 7) << 4)));
      }
#pragma unroll
      for (int ni = 0; ni < 4; ++ni) {
        const int row = wc * 64 + ni * 16 + lr;
        bfr[ni] = *(const bf16x8*)(bs + row * 128 + ((ks * 64 + lg * 16) ^ ((row & 7) << 4)));
      }
#pragma unroll
      for (int mi = 0; mi < 4; ++mi)
#pragma unroll
        for (int ni = 0; ni < 4; ++ni)
          acc[mi][ni] = MFMA16(af[mi], bfr[ni], acc[mi][ni]);
    }
    BARRIER();
    if (kt + 2 < nk) STAGE(cur, kt + 2);
    cur ^= 1;
  }

  if constexpr (MODE == 0) {
#pragma unroll
    for (int mi = 0; mi < 4; ++mi)
#pragma unroll
      for (int ni = 0; ni < 4; ++ni)
#pragma unroll
        for (int r = 0; r < 4; ++r) {
          const int row = m0 + wr * 64 + mi * 16 + lg * 4 + r;
          const int col = n0 + wc * 64 + ni * 16 + lr;
          out0[(size_t)row * N + col] = f2bf(acc[mi][ni][r] * scale0);
        }
  } else {
    const float sqs = 0.35355339059327379f;
#pragma unroll
    for (int mi = 0; mi < 4; ++mi)
#pragma unroll
      for (int ni = 0; ni < 4; ++ni)
#pragma unroll
        for (int r = 0; r < 4; ++r) {
          const int m = m0 + wr * 64 + mi * 16 + lg * 4 + r;  // b*2048+n
          const int col = n0 + wc * 64 + ni * 16 + lr;
          const float vv = acc[mi][ni][r];
          if (col < 1024) {
            out0[(size_t)m * 1024 + col] = f2bf(vv * scale0);                   // q
          } else {
            const int b = m >> 11, n = m & 2047;
            const int colk = col - 1024;
            if (colk < 64) {
              out1[(size_t)m * 64 + colk] = f2bf(vv * sqs);                     // k
            } else {
              const int d = colk - 64;
              out2[((size_t)b * 64 + d) * NSEQ + n] = f2bf(vv);                 // vT
            }
          }
        }
  }
}

// ---------------------------------------------------------------------------
// Causal flash attention (MQA: shared K/V per batch).
// Block = 256 thr (4 waves). Two q-tiles {i, 31-i} per block (balanced, 33
// tile-computes each). K/V dbuf + counted-vmcnt pipeline; XOR-swizzled LDS.
// S is in log2 units (log2e folded into q scaling) -> exp2f softmax.
// ---------------------------------------------------------------------------
__global__ __launch_bounds__(256) void attn_causal(const u16* __restrict__ Q,
                                                   const u16* __restrict__ Kg,
                                                   const u16* __restrict__ VTg,
                                                   u16* __restrict__ O) {
  const int pi = blockIdx.x;      // 0..15
  const int qtA = pi, qtB = 31 - pi;
  const int bh = blockIdx.y;      // 0..31
  const int b = bh >> 4, h = bh & 15;
  const int tid = threadIdx.x;
  const int w = tid >> 6, l = tid & 63;
  const int lr = l & 15, lg = l >> 4;

  __shared__ u16 Ks[2][64 * 64];   // [kv][d], swizzled, double-buffered
  __shared__ u16 Vs[2][64 * 64];   // [d][kv] (V^T), swizzled, double-buffered
  __shared__ u16 Ps[4][16 * 64];   // per-wave P, swizzled

  const int qrowA = qtA * 64 + w * 16 + lr;
  const int qrowB = qtB * 64 + w * 16 + lr;
  const size_t qbA = ((size_t)(b * NSEQ + qrowA)) * DIMC + h * DHEAD;
  const size_t qbB = ((size_t)(b * NSEQ + qrowB)) * DIMC + h * DHEAD;
  const bf16x8 aqA0 = *(const bf16x8*)(Q + qbA + lg * 8);
  const bf16x8 aqA1 = *(const bf16x8*)(Q + qbA + 32 + lg * 8);
  const bf16x8 aqB0 = *(const bf16x8*)(Q + qbB + lg * 8);
  const bf16x8 aqB1 = *(const bf16x8*)(Q + qbB + 32 + lg * 8);

  const char* kb = (const char*)(Kg + (size_t)b * NSEQ * DHEAD);
  const char* vb = (const char*)(VTg + (size_t)b * DHEAD * NSEQ);

  float mA[4], lA[4], mB[4], lB[4];
  f32x4 oA[4], oB[4];
#pragma unroll
  for (int r = 0; r < 4; ++r) { mA[r] = -1e30f; lA[r] = 0.f; mB[r] = -1e30f; lB[r] = 0.f; }
#pragma unroll
  for (int f = 0; f < 4; ++f) { oA[f] = f32x4{0.f,0.f,0.f,0.f}; oB[f] = f32x4{0.f,0.f,0.f,0.f}; }

  auto STAGE = [&](int buf, int kt) {
#pragma unroll
    for (int r = 0; r < 2; ++r) {
      const int c = w * 2 + r;
      const int lo = c * 1024 + l * 16;
      const int row = lo >> 7;   // 128 B per row
      const int pb = lo & 127;
      const int cl = pb ^ ((row & 7) << 4);  // inverse-swizzle the source
      gload_lds16(kb + (size_t)(kt * 64 + row) * 128 + cl, (char*)Ks[buf] + c * 1024);
      gload_lds16(vb + (size_t)row * (NSEQ * 2) + kt * 128 + cl, (char*)Vs[buf] + c * 1024);
    }
  };

  auto TILE = [&](const bf16x8 q0, const bf16x8 q1, float* mr, float* lsum,
                  f32x4* oa, int qt, int kt, int cur) {
    // S = Q @ K^T  -> [16 x 64] per wave (S in log2 units)
    f32x4 s[4];
    __builtin_amdgcn_s_setprio(1);
#pragma unroll
    for (int f = 0; f < 4; ++f) {
      s[f] = f32x4{0.f, 0.f, 0.f, 0.f};
      const int krow = f * 16 + lr;
      const char* krp = (const char*)Ks[cur] + krow * 128;
      const int ksw = (krow & 7) << 4;
      const bf16x8 b0 = *(const bf16x8*)(krp + ((lg * 16) ^ ksw));
      const bf16x8 b1 = *(const bf16x8*)(krp + ((64 + lg * 16) ^ ksw));
      s[f] = MFMA16(q0, b0, s[f]);
      s[f] = MFMA16(q1, b1, s[f]);
    }
    __builtin_amdgcn_s_setprio(0);

    if (kt == qt) {
#pragma unroll
      for (int f = 0; f < 4; ++f)
#pragma unroll
        for (int r = 0; r < 4; ++r)
          if (f * 16 + lr > w * 16 + lg * 4 + r) s[f][r] = -1e30f;
    }

    // online softmax in log2 domain (row = lg*4 + r; 16-lane group reduce)
    float pr[4][4];
#pragma unroll
    for (int r = 0; r < 4; ++r) {
      float mx = fmaxf(fmaxf(s[0][r], s[1][r]), fmaxf(s[2][r], s[3][r]));
#pragma unroll
      for (int d = 1; d < 16; d <<= 1) mx = fmaxf(mx, __shfl_xor(mx, d, 64));
      const float mnew = fmaxf(mr[r], mx);
      const float sc = exp2f(mr[r] - mnew);
      float ls = 0.f;
#pragma unroll
      for (int f = 0; f < 4; ++f) {
        const float p = exp2f(s[f][r] - mnew);
        pr[f][r] = p;
        ls += p;
      }
#pragma unroll
      for (int d = 1; d < 16; d <<= 1) ls += __shfl_xor(ls, d, 64);
      lsum[r] = lsum[r] * sc + ls;
      mr[r] = mnew;
#pragma unroll
      for (int f = 0; f < 4; ++f) oa[f][r] *= sc;
    }

    // P -> bf16 -> per-wave LDS (swizzled), then re-read as A-fragments
    u16* pw = &Ps[w][0];
#pragma unroll
    for (int f = 0; f < 4; ++f)
#pragma unroll
      for (int r = 0; r < 4; ++r) {
        const int row = lg * 4 + r;
        const int cbyte = (f * 16 + lr) * 2;
        *(u16*)((char*)pw + row * 128 + (cbyte ^ ((row & 7) << 4))) = f2bf(pr[f][r]);
      }

    const int psw = (lr & 7) << 4;
    const bf16x8 ap0 = *(const bf16x8*)((const char*)pw + lr * 128 + ((lg * 16) ^ psw));
    const bf16x8 ap1 = *(const bf16x8*)((const char*)pw + lr * 128 + ((64 + lg * 16) ^ psw));
    __builtin_amdgcn_s_setprio(1);
#pragma unroll
    for (int f = 0; f < 4; ++f) {
      const int vrow = f * 16 + lr;
      const char* vr = (const char*)Vs[cur] + vrow * 128;
      const int vsw = (vrow & 7) << 4;
      const bf16x8 b0 = *(const bf16x8*)(vr + ((lg * 16) ^ vsw));
      const bf16x8 b1 = *(const bf16x8*)(vr + ((64 + lg * 16) ^ vsw));
      oa[f] = MFMA16(ap0, b0, oa[f]);
      oa[f] = MFMA16(ap1, b1, oa[f]);
    }
    __builtin_amdgcn_s_setprio(0);
  };

  const int nkt = qtB + 1;
  STAGE(0, 0);
  STAGE(1, 1);   // nkt >= 17 always
  int cur = 0;
  for (int kt = 0; kt < nkt; ++kt) {
    if (kt + 1 < nkt) { WAIT_VM(4); } else { WAIT_VM(0); }
    BARRIER();
    if (kt <= qtA) TILE(aqA0, aqA1, mA, lA, oA, qtA, kt, cur);
    TILE(aqB0, aqB1, mB, lB, oB, qtB, kt, cur);
    BARRIER();
    if (kt + 2 < nkt) STAGE(cur, kt + 2);
    cur ^= 1;
  }

  float invA[4], invB[4];
#pragma unroll
  for (int r = 0; r < 4; ++r) { invA[r] = 1.f / lA[r]; invB[r] = 1.f / lB[r]; }
#pragma unroll
  for (int f = 0; f < 4; ++f)
#pragma unroll
    for (int r = 0; r < 4; ++r) {
      const int col = h * DHEAD + f * 16 + lr;
      const int rowA = qtA * 64 + w * 16 + lg * 4 + r;
      O[((size_t)(b * NSEQ + rowA)) * DIMC + col] = f2bf(oA[f][r] * invA[r]);
      const int rowB = qtB * 64 + w * 16 + lg * 4 + r;
      O[((size_t)(b * NSEQ + rowB)) * DIMC + col] = f2bf(oB[f][r] * invB[r]);
    }
}

// ---------------------------------------------------------------------------
extern "C" void kernel_launch(void* const* d_in, const int* in_sizes, int n_in,
                              void* d_out, int out_size, void* d_ws, size_t ws_size,
                              hipStream_t stream) {
  const float* x = (const float*)d_in[0];
  const float* w_q = (const float*)d_in[1];
  const float* w_kv = (const float*)d_in[2];
  const float* w_out = (const float*)d_in[3];
  const float* ln_g = (const float*)d_in[4];
  const float* ln_b = (const float*)d_in[5];
  const float* lno_g = (const float*)d_in[6];
  const float* lno_b = (const float*)d_in[7];
  float* out = (float*)d_out;

  char* ws = (char*)d_ws;
  size_t off = 0;
  auto alloc = [&](size_t bytes) {
    char* p = ws + off;
    off += (bytes + 255) & ~(size_t)255;
    return p;
  };
  u16* xn    = (u16*)alloc((size_t)BATCH * NSEQ * DIMC * 2);   // 8 MiB
  u16* wqkv  = (u16*)alloc((size_t)1152 * DIMC * 2);           // 2.25 MiB
  u16* wob   = (u16*)alloc((size_t)DIMC * DIMC * 2);           // 2 MiB
  u16* qb    = (u16*)alloc((size_t)BATCH * NSEQ * DIMC * 2);   // 8 MiB
  u16* kb    = (u16*)alloc((size_t)BATCH * NSEQ * DHEAD * 2);  // 512 KiB
  u16* vtb   = (u16*)alloc((size_t)BATCH * DHEAD * NSEQ * 2);  // 512 KiB
  u16* ao = xn;  // attention output aliases xn (xn dead after projections)
  u16* yb = qb;  // pre-LN2 aliases q (q dead after attention)

  // scale * sqrt(scale) * log2(e)  (softmax runs in log2 domain)
  const float qscale = (float)(0.044194173824159216 * 1.4426950408889634);

  cvt_f32_bf16<<<1024, 256, 0, stream>>>(w_q, wqkv, DIMC * DIMC);
  cvt_f32_bf16<<<128, 256, 0, stream>>>(w_kv, wqkv + (size_t)DIMC * DIMC, 128 * DIMC);
  cvt_f32_bf16<<<1024, 256, 0, stream>>>(w_out, wob, DIMC * DIMC);

  ln_f32_to_bf16<<<BATCH * NSEQ, 256, 0, stream>>>(x, ln_g, ln_b, xn);

  // fused Q + KV projection: N = 1152 (grid 9x32 = 288 blocks, %8==0)
  gemm_bt<2><<<dim3(9, 32), 256, 0, stream>>>(xn, wqkv, qb, kb, vtb,
                                              BATCH * NSEQ, 1152, DIMC, qscale);

  attn_causal<<<dim3(16, 32), 256, 0, stream>>>(qb, kb, vtb, ao);

  gemm_bt<0><<<dim3(8, 32), 256, 0, stream>>>(ao, wob, yb, nullptr, nullptr,
                                              BATCH * NSEQ, DIMC, DIMC, 1.f);

  ln_bf16_to_f32<<<BATCH * NSEQ, 256, 0, stream>>>(yb, lno_g, lno_b, out);
}

// Round 5
// 201.854 us; speedup vs baseline: 1.4542x; 1.0440x over previous
//
#include <hip/hip_runtime.h>
#include <hip/hip_bf16.h>
#include <stdint.h>

typedef unsigned short u16;
typedef __bf16 bf16x8 __attribute__((ext_vector_type(8)));
typedef float f32x4 __attribute__((ext_vector_type(4)));

#define MFMA16(a, b, c) __builtin_amdgcn_mfma_f32_16x16x32_bf16((a), (b), (c), 0, 0, 0)

#define BATCH 2
#define NSEQ 2048
#define DIMC 1024
#define NHEAD 16
#define DHEAD 64

__device__ __forceinline__ u16 f2bf(float f) {
  unsigned u = __float_as_uint(f);
  u += 0x7FFFu + ((u >> 16) & 1u);
  return (u16)(u >> 16);
}
__device__ __forceinline__ float bf2f(u16 h) {
  return __uint_as_float(((unsigned)h) << 16);
}
__device__ __forceinline__ void gload_lds16(const void* g, void* lds) {
  __builtin_amdgcn_global_load_lds((const __attribute__((address_space(1))) void*)g,
                                   (__attribute__((address_space(3))) void*)lds,
                                   16, 0, 0);
}
// counted-vmcnt waits (immediates must be literals)
#define WAIT_VM(N) asm volatile("s_waitcnt vmcnt(" #N ")" ::: "memory")
#define BARRIER() __builtin_amdgcn_s_barrier()

// ---------------------------------------------------------------------------
// fp32 -> bf16 conversion (weights)
// ---------------------------------------------------------------------------
__global__ __launch_bounds__(256) void cvt_f32_bf16(const float* __restrict__ in,
                                                    u16* __restrict__ out, int n) {
  int i = (blockIdx.x * 256 + threadIdx.x) * 4;
  if (i < n) {
    float4 v = *(const float4*)(in + i);
    ushort4 o;
    o.x = f2bf(v.x); o.y = f2bf(v.y); o.z = f2bf(v.z); o.w = f2bf(v.w);
    *(ushort4*)(out + i) = o;
  }
}

// ---------------------------------------------------------------------------
// LayerNorm: fp32 in -> bf16 out   (one block per row, 1024 cols)
// ---------------------------------------------------------------------------
__global__ __launch_bounds__(256) void ln_f32_to_bf16(const float* __restrict__ X,
                                                      const float* __restrict__ G,
                                                      const float* __restrict__ Bv,
                                                      u16* __restrict__ Y) {
  const int row = blockIdx.x;
  const int tid = threadIdx.x;
  const float4 v = *(const float4*)(X + (size_t)row * DIMC + tid * 4);
  float s = v.x + v.y + v.z + v.w;
  float q = v.x * v.x + v.y * v.y + v.z * v.z + v.w * v.w;
#pragma unroll
  for (int d = 1; d < 64; d <<= 1) {
    s += __shfl_xor(s, d, 64);
    q += __shfl_xor(q, d, 64);
  }
  __shared__ float ps[4], pq[4];
  const int w = tid >> 6, l = tid & 63;
  if (l == 0) { ps[w] = s; pq[w] = q; }
  __syncthreads();
  s = ps[0] + ps[1] + ps[2] + ps[3];
  q = pq[0] + pq[1] + pq[2] + pq[3];
  const float mean = s * (1.f / DIMC);
  const float var = q * (1.f / DIMC) - mean * mean;
  const float rs = rsqrtf(var + 1e-5f);
  const float4 g = *(const float4*)(G + tid * 4);
  const float4 bb = *(const float4*)(Bv + tid * 4);
  ushort4 o;
  o.x = f2bf((v.x - mean) * rs * g.x + bb.x);
  o.y = f2bf((v.y - mean) * rs * g.y + bb.y);
  o.z = f2bf((v.z - mean) * rs * g.z + bb.z);
  o.w = f2bf((v.w - mean) * rs * g.w + bb.w);
  *(ushort4*)(Y + (size_t)row * DIMC + tid * 4) = o;
}

// LayerNorm: bf16 in -> fp32 out
__global__ __launch_bounds__(256) void ln_bf16_to_f32(const u16* __restrict__ X,
                                                      const float* __restrict__ G,
                                                      const float* __restrict__ Bv,
                                                      float* __restrict__ Y) {
  const int row = blockIdx.x;
  const int tid = threadIdx.x;
  const ushort4 hv = *(const ushort4*)(X + (size_t)row * DIMC + tid * 4);
  float x0 = bf2f(hv.x), x1 = bf2f(hv.y), x2 = bf2f(hv.z), x3 = bf2f(hv.w);
  float s = x0 + x1 + x2 + x3;
  float q = x0 * x0 + x1 * x1 + x2 * x2 + x3 * x3;
#pragma unroll
  for (int d = 1; d < 64; d <<= 1) {
    s += __shfl_xor(s, d, 64);
    q += __shfl_xor(q, d, 64);
  }
  __shared__ float ps[4], pq[4];
  const int w = tid >> 6, l = tid & 63;
  if (l == 0) { ps[w] = s; pq[w] = q; }
  __syncthreads();
  s = ps[0] + ps[1] + ps[2] + ps[3];
  q = pq[0] + pq[1] + pq[2] + pq[3];
  const float mean = s * (1.f / DIMC);
  const float var = q * (1.f / DIMC) - mean * mean;
  const float rs = rsqrtf(var + 1e-5f);
  const float4 g = *(const float4*)(G + tid * 4);
  const float4 bb = *(const float4*)(Bv + tid * 4);
  float4 o;
  o.x = (x0 - mean) * rs * g.x + bb.x;
  o.y = (x1 - mean) * rs * g.y + bb.y;
  o.z = (x2 - mean) * rs * g.z + bb.z;
  o.w = (x3 - mean) * rs * g.w + bb.w;
  *(float4*)(Y + (size_t)row * DIMC + tid * 4) = o;
}

// ---------------------------------------------------------------------------
// GEMM  C[M,N] = A[M,K] @ Bw[N,K]^T   (bf16 in, fp32 acc)
// 128x128 tile, BK=64, 512 threads (8 waves, 2M x 4N; wave = 64x32, acc 4x2).
// dbuf + counted-vmcnt pipeline, XOR-swizzled LDS, XCD-chunked block swizzle.
// MODE 0: out0[m][n] = bf16(acc * scale0)
// MODE 2: fused QKV (N=1152): col<1024 -> q*scale0 ; 1024..1087 -> k*sqs ;
//         1088..1151 -> vT[b][d][n]
// ---------------------------------------------------------------------------
template <int MODE>
__global__ __launch_bounds__(512) void gemm_bt(const u16* __restrict__ A,
                                               const u16* __restrict__ Bw,
                                               u16* __restrict__ out0,
                                               u16* __restrict__ out1,
                                               u16* __restrict__ out2,
                                               int M, int N, int K, float scale0) {
  const int tid = threadIdx.x;
  const int w = tid >> 6, l = tid & 63;
  const int wr = w >> 2, wc = w & 3;
  const int lr = l & 15, lg = l >> 4;

  // XCD-chunked bijective swizzle (nwg % 8 == 0 guaranteed by launch)
  const int nwgx = gridDim.x;
  const int nwg = nwgx * gridDim.y;
  int flat = blockIdx.x + nwgx * blockIdx.y;
  flat = (flat & 7) * (nwg >> 3) + (flat >> 3);
  const int m0 = (flat / nwgx) * 128, n0 = (flat % nwgx) * 128;

  __shared__ u16 As[2][128 * 64];   // 16 KiB each, 128B rows, XOR-swizzled
  __shared__ u16 Bs[2][128 * 64];

  f32x4 acc[4][2] = {};

  auto STAGE = [&](int buf, int kt) {
#pragma unroll
    for (int r = 0; r < 2; ++r) {
      const int c = w * 2 + r;          // chunk 0..15, 1 KiB each
      const int lo = c * 1024 + l * 16;
      const int row = lo >> 7;          // 128 B per row (64 bf16)
      const int cl = (lo & 127) ^ ((row & 7) << 4);  // inverse-swizzle source
      gload_lds16((const char*)A + ((size_t)(m0 + row) * K + kt * 64) * 2 + cl,
                  (char*)As[buf] + c * 1024);
      gload_lds16((const char*)Bw + ((size_t)(n0 + row) * K + kt * 64) * 2 + cl,
                  (char*)Bs[buf] + c * 1024);
    }
  };

  const int nk = K >> 6;
  STAGE(0, 0);
  STAGE(1, 1);          // K >= 128 always here
  int cur = 0;
  for (int kt = 0; kt < nk; ++kt) {
    if (kt + 1 < nk) { WAIT_VM(4); } else { WAIT_VM(0); }
    BARRIER();
    const char* as = (const char*)As[cur];
    const char* bs = (const char*)Bs[cur];
#pragma unroll
    for (int ks = 0; ks < 2; ++ks) {
      bf16x8 af[4], bfr[2];
#pragma unroll
      for (int mi = 0; mi < 4; ++mi) {
        const int row = wr * 64 + mi * 16 + lr;
        af[mi] = *(const bf16x8*)(as + row * 128 + ((ks * 64 + lg * 16) ^ ((row & 7) << 4)));
      }
#pragma unroll
      for (int ni = 0; ni < 2; ++ni) {
        const int row = wc * 32 + ni * 16 + lr;
        bfr[ni] = *(const bf16x8*)(bs + row * 128 + ((ks * 64 + lg * 16) ^ ((row & 7) << 4)));
      }
      __builtin_amdgcn_s_setprio(1);
#pragma unroll
      for (int mi = 0; mi < 4; ++mi)
#pragma unroll
        for (int ni = 0; ni < 2; ++ni)
          acc[mi][ni] = MFMA16(af[mi], bfr[ni], acc[mi][ni]);
      __builtin_amdgcn_s_setprio(0);
    }
    BARRIER();
    if (kt + 2 < nk) STAGE(cur, kt + 2);
    cur ^= 1;
  }

  if constexpr (MODE == 0) {
#pragma unroll
    for (int mi = 0; mi < 4; ++mi)
#pragma unroll
      for (int ni = 0; ni < 2; ++ni)
#pragma unroll
        for (int r = 0; r < 4; ++r) {
          const int row = m0 + wr * 64 + mi * 16 + lg * 4 + r;
          const int col = n0 + wc * 32 + ni * 16 + lr;
          out0[(size_t)row * N + col] = f2bf(acc[mi][ni][r] * scale0);
        }
  } else {
    const float sqs = 0.35355339059327379f;
#pragma unroll
    for (int mi = 0; mi < 4; ++mi)
#pragma unroll
      for (int ni = 0; ni < 2; ++ni)
#pragma unroll
        for (int r = 0; r < 4; ++r) {
          const int m = m0 + wr * 64 + mi * 16 + lg * 4 + r;  // b*2048+n
          const int col = n0 + wc * 32 + ni * 16 + lr;
          const float vv = acc[mi][ni][r];
          if (col < 1024) {
            out0[(size_t)m * 1024 + col] = f2bf(vv * scale0);                   // q
          } else {
            const int b = m >> 11, n = m & 2047;
            const int colk = col - 1024;
            if (colk < 64) {
              out1[(size_t)m * 64 + colk] = f2bf(vv * sqs);                     // k
            } else {
              const int d = colk - 64;
              out2[((size_t)b * 64 + d) * NSEQ + n] = f2bf(vv);                 // vT
            }
          }
        }
  }
}

// ---------------------------------------------------------------------------
// Causal flash attention (MQA: shared K/V per batch).
// Block = 256 thr (4 waves). Two q-tiles {i, 31-i} per block (balanced:
// 17 kv-tile computes each). KVBLK=128. K/V dbuf + counted-vmcnt pipeline;
// XOR-swizzled LDS. log2-domain softmax, defer-rescale (THR=6), truncating
// bf16 P-store.
// ---------------------------------------------------------------------------
__global__ __launch_bounds__(256) void attn_causal(const u16* __restrict__ Q,
                                                   const u16* __restrict__ Kg,
                                                   const u16* __restrict__ VTg,
                                                   u16* __restrict__ O) {
  const int pi = blockIdx.x;      // 0..15
  const int qtA = pi, qtB = 31 - pi;
  const int bh = blockIdx.y;      // 0..31
  const int b = bh >> 4, h = bh & 15;
  const int tid = threadIdx.x;
  const int w = tid >> 6, l = tid & 63;
  const int lr = l & 15, lg = l >> 4;

  __shared__ u16 Ks[2][128 * 64];   // [kv 128][d 64], 128B rows, swizzled
  __shared__ u16 Vs[2][64 * 128];   // [d 64][kv 128] (V^T), 256B rows, swizzled
  __shared__ u16 Ps[4][16 * 128];   // per-wave P, 256B rows, swizzled

  const int qrowA = qtA * 64 + w * 16 + lr;
  const int qrowB = qtB * 64 + w * 16 + lr;
  const size_t qbA = ((size_t)(b * NSEQ + qrowA)) * DIMC + h * DHEAD;
  const size_t qbB = ((size_t)(b * NSEQ + qrowB)) * DIMC + h * DHEAD;
  const bf16x8 aqA0 = *(const bf16x8*)(Q + qbA + lg * 8);
  const bf16x8 aqA1 = *(const bf16x8*)(Q + qbA + 32 + lg * 8);
  const bf16x8 aqB0 = *(const bf16x8*)(Q + qbB + lg * 8);
  const bf16x8 aqB1 = *(const bf16x8*)(Q + qbB + 32 + lg * 8);

  const char* kb = (const char*)(Kg + (size_t)b * NSEQ * DHEAD);
  const char* vb = (const char*)(VTg + (size_t)b * DHEAD * NSEQ);

  float mA[4], lA[4], mB[4], lB[4];
  f32x4 oA[4], oB[4];
#pragma unroll
  for (int r = 0; r < 4; ++r) { mA[r] = -1e30f; lA[r] = 0.f; mB[r] = -1e30f; lB[r] = 0.f; }
#pragma unroll
  for (int f = 0; f < 4; ++f) { oA[f] = f32x4{0.f,0.f,0.f,0.f}; oB[f] = f32x4{0.f,0.f,0.f,0.f}; }

  auto STAGE = [&](int buf, int ktv) {
#pragma unroll
    for (int r = 0; r < 4; ++r) {
      const int c = w * 4 + r;            // chunk 0..15, 1 KiB each
      const int lo = c * 1024 + l * 16;
      // K: 128B rows
      const int krow = lo >> 7;
      const int kcl = (lo & 127) ^ ((krow & 7) << 4);
      gload_lds16(kb + (size_t)(ktv * 128 + krow) * 128 + kcl, (char*)Ks[buf] + c * 1024);
      // V^T: 256B rows
      const int vrow = lo >> 8;
      const int vcl = (lo & 255) ^ ((vrow & 7) << 4);
      gload_lds16(vb + (size_t)vrow * (NSEQ * 2) + ktv * 256 + vcl, (char*)Vs[buf] + c * 1024);
    }
  };

  auto TILE = [&](const bf16x8 q0, const bf16x8 q1, float* mr, float* lsum,
                  f32x4* oa, int qt, int ktv, int cur) {
    // S = Q @ K^T  -> [16 x 128] per wave (log2 units). s[f][r]:
    // kv = ktv*128 + f*16 + lr ; q-row = qt*64 + w*16 + lg*4 + r
    f32x4 s[8];
    __builtin_amdgcn_s_setprio(1);
#pragma unroll
    for (int f = 0; f < 8; ++f) {
      s[f] = f32x4{0.f, 0.f, 0.f, 0.f};
      const int krow = f * 16 + lr;
      const char* krp = (const char*)Ks[cur] + krow * 128;
      const int ksw = (krow & 7) << 4;
      const bf16x8 b0 = *(const bf16x8*)(krp + ((lg * 16) ^ ksw));
      const bf16x8 b1 = *(const bf16x8*)(krp + ((64 + lg * 16) ^ ksw));
      s[f] = MFMA16(q0, b0, s[f]);
      s[f] = MFMA16(q1, b1, s[f]);
    }
    __builtin_amdgcn_s_setprio(0);

    if (ktv == (qt >> 1)) {
#pragma unroll
      for (int f = 0; f < 8; ++f)
#pragma unroll
        for (int r = 0; r < 4; ++r)
          if (ktv * 128 + f * 16 + lr > qt * 64 + w * 16 + lg * 4 + r) s[f][r] = -1e30f;
    }

    // tile max per row
    float mx[4];
#pragma unroll
    for (int r = 0; r < 4; ++r) {
      float m0_ = fmaxf(fmaxf(s[0][r], s[1][r]), fmaxf(s[2][r], s[3][r]));
      float m1_ = fmaxf(fmaxf(s[4][r], s[5][r]), fmaxf(s[6][r], s[7][r]));
      float v = fmaxf(m0_, m1_);
#pragma unroll
      for (int d = 1; d < 16; d <<= 1) v = fmaxf(v, __shfl_xor(v, d, 64));
      mx[r] = v;
    }
    // defer-rescale: only rescale when some row grew by > 6 (log2 units)
    const bool grow = (mx[0] - mr[0] > 6.f) || (mx[1] - mr[1] > 6.f) ||
                      (mx[2] - mr[2] > 6.f) || (mx[3] - mr[3] > 6.f);
    if (__any(grow)) {
#pragma unroll
      for (int r = 0; r < 4; ++r) {
        const float mnew = fmaxf(mr[r], mx[r]);
        const float sc = exp2f(mr[r] - mnew);
        lsum[r] *= sc;
        mr[r] = mnew;
#pragma unroll
        for (int f = 0; f < 4; ++f) oa[f][r] *= sc;
      }
    }
    // P = exp2(S - m), accumulate row sums
#pragma unroll
    for (int r = 0; r < 4; ++r) {
      float ls = 0.f;
#pragma unroll
      for (int f = 0; f < 8; ++f) {
        const float p = exp2f(s[f][r] - mr[r]);
        s[f][r] = p;
        ls += p;
      }
#pragma unroll
      for (int d = 1; d < 16; d <<= 1) ls += __shfl_xor(ls, d, 64);
      lsum[r] += ls;
    }

    // P -> bf16 (truncate) -> per-wave LDS (swizzled)
    u16* pw = &Ps[w][0];
#pragma unroll
    for (int f = 0; f < 8; ++f)
#pragma unroll
      for (int r = 0; r < 4; ++r) {
        const int row = lg * 4 + r;
        const int cbyte = (f * 16 + lr) * 2;
        *(u16*)((char*)pw + row * 256 + (cbyte ^ ((row & 7) << 4))) =
            (u16)(__float_as_uint(s[f][r]) >> 16);
      }

    // re-read P as A-fragments, PV
    const int psw = (lr & 7) << 4;
    bf16x8 ap[4];
#pragma unroll
    for (int ks = 0; ks < 4; ++ks)
      ap[ks] = *(const bf16x8*)((const char*)pw + lr * 256 + ((ks * 64 + lg * 16) ^ psw));
    __builtin_amdgcn_s_setprio(1);
#pragma unroll
    for (int f = 0; f < 4; ++f) {
      const int vrow = f * 16 + lr;
      const char* vr = (const char*)Vs[cur] + vrow * 256;
      const int vsw = (vrow & 7) << 4;
#pragma unroll
      for (int ks = 0; ks < 4; ++ks) {
        const bf16x8 vf = *(const bf16x8*)(vr + ((ks * 64 + lg * 16) ^ vsw));
        oa[f] = MFMA16(ap[ks], vf, oa[f]);
      }
    }
    __builtin_amdgcn_s_setprio(0);
  };

  const int nkt = (qtB >> 1) + 1;   // >= 9
  const int lastA = qtA >> 1;
  STAGE(0, 0);
  STAGE(1, 1);
  int cur = 0;
  for (int ktv = 0; ktv < nkt; ++ktv) {
    if (ktv + 1 < nkt) { WAIT_VM(8); } else { WAIT_VM(0); }
    BARRIER();
    if (ktv <= lastA) TILE(aqA0, aqA1, mA, lA, oA, qtA, ktv, cur);
    TILE(aqB0, aqB1, mB, lB, oB, qtB, ktv, cur);
    BARRIER();
    if (ktv + 2 < nkt) STAGE(cur, ktv + 2);
    cur ^= 1;
  }

  float invA[4], invB[4];
#pragma unroll
  for (int r = 0; r < 4; ++r) { invA[r] = 1.f / lA[r]; invB[r] = 1.f / lB[r]; }
#pragma unroll
  for (int f = 0; f < 4; ++f)
#pragma unroll
    for (int r = 0; r < 4; ++r) {
      const int col = h * DHEAD + f * 16 + lr;
      const int rowA = qtA * 64 + w * 16 + lg * 4 + r;
      O[((size_t)(b * NSEQ + rowA)) * DIMC + col] = f2bf(oA[f][r] * invA[r]);
      const int rowB = qtB * 64 + w * 16 + lg * 4 + r;
      O[((size_t)(b * NSEQ + rowB)) * DIMC + col] = f2bf(oB[f][r] * invB[r]);
    }
}

// ---------------------------------------------------------------------------
extern "C" void kernel_launch(void* const* d_in, const int* in_sizes, int n_in,
                              void* d_out, int out_size, void* d_ws, size_t ws_size,
                              hipStream_t stream) {
  const float* x = (const float*)d_in[0];
  const float* w_q = (const float*)d_in[1];
  const float* w_kv = (const float*)d_in[2];
  const float* w_out = (const float*)d_in[3];
  const float* ln_g = (const float*)d_in[4];
  const float* ln_b = (const float*)d_in[5];
  const float* lno_g = (const float*)d_in[6];
  const float* lno_b = (const float*)d_in[7];
  float* out = (float*)d_out;

  char* ws = (char*)d_ws;
  size_t off = 0;
  auto alloc = [&](size_t bytes) {
    char* p = ws + off;
    off += (bytes + 255) & ~(size_t)255;
    return p;
  };
  u16* xn    = (u16*)alloc((size_t)BATCH * NSEQ * DIMC * 2);   // 8 MiB
  u16* wqkv  = (u16*)alloc((size_t)1152 * DIMC * 2);           // 2.25 MiB
  u16* wob   = (u16*)alloc((size_t)DIMC * DIMC * 2);           // 2 MiB
  u16* qb    = (u16*)alloc((size_t)BATCH * NSEQ * DIMC * 2);   // 8 MiB
  u16* kb    = (u16*)alloc((size_t)BATCH * NSEQ * DHEAD * 2);  // 512 KiB
  u16* vtb   = (u16*)alloc((size_t)BATCH * DHEAD * NSEQ * 2);  // 512 KiB
  u16* ao = xn;  // attention output aliases xn (xn dead after projections)
  u16* yb = qb;  // pre-LN2 aliases q (q dead after attention)

  // scale * sqrt(scale) * log2(e)  (softmax runs in log2 domain)
  const float qscale = (float)(0.044194173824159216 * 1.4426950408889634);

  cvt_f32_bf16<<<1024, 256, 0, stream>>>(w_q, wqkv, DIMC * DIMC);
  cvt_f32_bf16<<<128, 256, 0, stream>>>(w_kv, wqkv + (size_t)DIMC * DIMC, 128 * DIMC);
  cvt_f32_bf16<<<1024, 256, 0, stream>>>(w_out, wob, DIMC * DIMC);

  ln_f32_to_bf16<<<BATCH * NSEQ, 256, 0, stream>>>(x, ln_g, ln_b, xn);

  // fused Q + KV projection: N = 1152 (grid 9x32 = 288 blocks, %8==0)
  gemm_bt<2><<<dim3(9, 32), 512, 0, stream>>>(xn, wqkv, qb, kb, vtb,
                                              BATCH * NSEQ, 1152, DIMC, qscale);

  attn_causal<<<dim3(16, 32), 256, 0, stream>>>(qb, kb, vtb, ao);

  gemm_bt<0><<<dim3(8, 32), 512, 0, stream>>>(ao, wob, yb, nullptr, nullptr,
                                              BATCH * NSEQ, DIMC, DIMC, 1.f);

  ln_bf16_to_f32<<<BATCH * NSEQ, 256, 0, stream>>>(yb, lno_g, lno_b, out);
}